// Round 7
// baseline (1453.469 us; speedup 1.0000x reference)
//
#include <hip/hip_runtime.h>
#include <stdint.h>

typedef unsigned long long u64;
typedef unsigned int u32;
using short8  = __attribute__((ext_vector_type(8))) short;
using f32x16  = __attribute__((ext_vector_type(16))) float;

__constant__ int c_LN[5]   = {76800, 19200, 4800, 1200, 300}; // H*H*3 per level
__constant__ int c_LOFF[5] = {0, 76800, 96000, 100800, 102000};
__constant__ int c_KK[5]   = {1000, 1000, 1000, 1000, 300};   // k1 = min(1000, N)

#define TOT_PL 102300
#define BBCLIP 4.1351665567423560f

__device__ __forceinline__ u32 fkey(float f) {
  u32 b = __float_as_uint(f);
  return b ^ (u32)(((int)b >> 31) | 0x80000000u);
}

template<int NELEM, int NTHR>
__device__ __forceinline__ void bitonic_desc(u64* sb, int t) {
  constexpr int PAIRS = NELEM / 2;
  for (int size = 2; size <= NELEM; size <<= 1) {
    for (int stride = size >> 1; stride > 0; stride >>= 1) {
      __syncthreads();
      for (int i = t; i < PAIRS; i += NTHR) {
        int pos = 2 * i - (i & (stride - 1));
        u64 a = sb[pos], b = sb[pos + stride];
        bool desc = ((pos & size) == 0);
        if (desc ? (a < b) : (a > b)) { sb[pos] = b; sb[pos + stride] = a; }
      }
    }
  }
  __syncthreads();
}

// ---------------- K0: pre-transpose weights, 3-way bf16 split ----------------
// chunk ca = tap*16 + g covers k [16ca,16ca+16): ci = g*16 + kloc, kloc = half*8 + j.
// Wt u16 layout: slice = (ca*6 + split*2 + half); within slice: co granule of 8 u16.
__global__ __launch_bounds__(256) void prep_weights(
    const float* __restrict__ Wf, unsigned short* __restrict__ Wt)
{
  int idx = blockIdx.x * 256 + threadIdx.x;   // E = 2304*256
  if (idx >= 589824) return;
  int co = idx & 255;
  int k2 = idx >> 8;            // 0..2303
  int chunk = k2 >> 4, kloc = k2 & 15;
  int tap = chunk / 16, g = chunk & 15;
  int ci = (g << 4) + kloc;
  float v = Wf[co * 2304 + ci * 9 + tap];
  u32 u0 = __float_as_uint(v) & 0xFFFF0000u;
  float r1 = v - __uint_as_float(u0);
  u32 u1 = __float_as_uint(r1) & 0xFFFF0000u;
  float r2 = r1 - __uint_as_float(u1);
  u32 u2 = __float_as_uint(r2) & 0xFFFF0000u;
  int half = kloc >> 3, j = kloc & 7;
  int base = (chunk * 6 + half) * 2048 + co * 8 + j;   // +4096 u16 per split
  Wt[base]          = (unsigned short)(u0 >> 16);
  Wt[base + 4096]   = (unsigned short)(u1 >> 16);
  Wt[base + 8192]   = (unsigned short)(u2 >> 16);
}

// ---------------- K1: fused all-level 3x3 conv via MFMA ----------------
// One dispatch covers all 5 levels (S=1). Per block: 128co x 128px tile,
// double-buffered halo LDS, register prefetch of next ci-block, A-frags direct
// from global Wt (whole-value short8 loads - no local-array address casts).
// 1 barrier per ci-block (16 total).
__global__ __launch_bounds__(256, 3) void conv_mega(
    const float* __restrict__ f0, const float* __restrict__ f1,
    const float* __restrict__ f2, const float* __restrict__ f3,
    const float* __restrict__ f4,
    const u32* __restrict__ Wt32, const float* __restrict__ bf,
    float* __restrict__ rfbase, int bid0, int rfmode)
{
  __shared__ u32 haloPd[9600];     // 2 x 4800 u32 = 38.4 KB
  const int t = threadIdx.x;
  int b = blockIdx.x + bid0;
  int l = 0, boff = 0;
  if (b >= 800)  { l = 1; boff = 800; }
  if (b >= 1000) { l = 2; boff = 1000; }
  if (b >= 1060) { l = 3; boff = 1060; }
  if (b >= 1084) { l = 4; boff = 1084; }
  const int H = 160 >> l, W = H, HW = H * W;
  const int tiles_x = (W + 15) >> 4;
  const int T = tiles_x * ((H + 7) >> 3);
  int local = b - boff;
  int tile = local % T, rest = local / T;
  const int cob = (rest & 1) * 128;
  const int n = rest >> 1;
  int tx = tile % tiles_x, ty = tile / tiles_x;
  const int c0 = tx * 16, r0 = ty * 8;
  const float* feat = (l == 0) ? f0 : (l == 1) ? f1 : (l == 2) ? f2 : (l == 3) ? f3 : f4;
  const float* featN = feat + (size_t)n * 256 * HW;
  int cum = (102400 - 4 * HW) / 3;
  if (rfmode && l >= 1) cum -= 25600;
  float* outp = rfbase + (size_t)512 * cum;
  const short8* WtV = (const short8*)Wt32;

  const int lane = t & 63;
  const int wave = t >> 6;
  const int wy = wave >> 1, wx = wave & 1;
  const int fh = lane >> 5;
  const int ln31 = lane & 31;

  // ---- halo staging precompute (fixed per thread) ----
  int offsp[7], ostore[7], cio[7];
  bool vOK[7], sOK[7];
#pragma unroll
  for (int i = 0; i < 7; i++) {
    int e2 = t + i * 256;
    sOK[i] = (e2 < 1600);
    int pp = e2 & 3, q = e2 >> 2;
    int half = q / 200, rem = q - half * 200;
    int y = rem / 20, x = rem - y * 20;
    int gy = r0 + y - 1, gx = c0 + x - 1;
    bool val = sOK[i] && (x < 18) && ((unsigned)gy < (unsigned)H) && ((unsigned)gx < (unsigned)W);
    vOK[i] = val;
    offsp[i] = val ? (gy * W + gx) : 0;
    cio[i] = half * 8 + pp * 2;
    ostore[i] = half * 800 + rem * 4 + pp;
  }

  f32x16 acc[2][2];
#pragma unroll
  for (int i = 0; i < 2; i++)
#pragma unroll
    for (int j = 0; j < 2; j++)
#pragma unroll
      for (int e = 0; e < 16; e++) acc[i][j][e] = 0.f;

  float ra[7], rb[7];
  // prologue: load ci-block 0
#pragma unroll
  for (int i = 0; i < 7; i++) {
    const float* p = featN + (size_t)cio[i] * HW + offsp[i];
    ra[i] = vOK[i] ? p[0] : 0.f;
    rb[i] = vOK[i] ? p[HW] : 0.f;
  }

  for (int g = 0; g < 16; g++) {
    // ---- split + store into buffer g&1 ----
    {
      u32* hp = &haloPd[(g & 1) * 4800];
#pragma unroll
      for (int i = 0; i < 7; i++) {
        if (sOK[i]) {
          float a = ra[i], bv = rb[i];
          u32 a0 = __float_as_uint(a) & 0xFFFF0000u;
          float ar1 = a - __uint_as_float(a0);
          u32 a1 = __float_as_uint(ar1) & 0xFFFF0000u;
          float ar2 = ar1 - __uint_as_float(a1);
          u32 a2 = __float_as_uint(ar2) & 0xFFFF0000u;
          u32 b0 = __float_as_uint(bv) & 0xFFFF0000u;
          float br1 = bv - __uint_as_float(b0);
          u32 b1 = __float_as_uint(br1) & 0xFFFF0000u;
          float br2 = br1 - __uint_as_float(b1);
          u32 b2 = __float_as_uint(br2) & 0xFFFF0000u;
          int o = ostore[i];
          hp[o]        = (a0 >> 16) | b0;
          hp[o + 1600] = (a1 >> 16) | b1;
          hp[o + 3200] = (a2 >> 16) | b2;
        }
      }
    }
    __syncthreads();
    // ---- prefetch next ci-block into registers (no wait) ----
    if (g < 15) {
      const float* fgn = featN + (size_t)((g + 1) << 4) * HW;
#pragma unroll
      for (int i = 0; i < 7; i++) {
        const float* p = fgn + (size_t)cio[i] * HW + offsp[i];
        ra[i] = vOK[i] ? p[0] : 0.f;
        rb[i] = vOK[i] ? p[HW] : 0.f;
      }
    }
    // ---- 9 taps, no barriers ----
    const u32* hp = &haloPd[(g & 1) * 4800];
    for (int tap = 0; tap < 9; tap++) {
      const int ca = tap * 16 + g;
      short8 aT[3][2], bT[3][2];
      const int tdy = tap / 3, tdx = tap - tdy * 3;
#pragma unroll
      for (int sp = 0; sp < 3; sp++) {
#pragma unroll
        for (int ti = 0; ti < 2; ti++)
          aT[sp][ti] = WtV[(size_t)(ca * 6 + sp * 2 + fh) * 256 + cob + wy * 64 + ti * 32 + ln31];
#pragma unroll
        for (int tj = 0; tj < 2; tj++) {
          int px = wx * 64 + tj * 32 + ln31;
          int pos = ((px >> 4) + tdy) * 20 + (px & 15) + tdx;
          bT[sp][tj] = *(const short8*)&hp[(sp * 2 + fh) * 800 + pos * 4];
        }
      }
#pragma unroll
      for (int ti = 0; ti < 2; ti++)
#pragma unroll
        for (int tj = 0; tj < 2; tj++) {
          acc[ti][tj] = __builtin_amdgcn_mfma_f32_32x32x16_bf16(aT[1][ti], bT[1][tj], acc[ti][tj], 0, 0, 0);
          acc[ti][tj] = __builtin_amdgcn_mfma_f32_32x32x16_bf16(aT[0][ti], bT[2][tj], acc[ti][tj], 0, 0, 0);
          acc[ti][tj] = __builtin_amdgcn_mfma_f32_32x32x16_bf16(aT[2][ti], bT[0][tj], acc[ti][tj], 0, 0, 0);
          acc[ti][tj] = __builtin_amdgcn_mfma_f32_32x32x16_bf16(aT[0][ti], bT[1][tj], acc[ti][tj], 0, 0, 0);
          acc[ti][tj] = __builtin_amdgcn_mfma_f32_32x32x16_bf16(aT[1][ti], bT[0][tj], acc[ti][tj], 0, 0, 0);
          acc[ti][tj] = __builtin_amdgcn_mfma_f32_32x32x16_bf16(aT[0][ti], bT[0][tj], acc[ti][tj], 0, 0, 0);
        }
    }
  }

  // ---- epilogue: bias + relu, write rf ----
#pragma unroll
  for (int ti = 0; ti < 2; ti++)
#pragma unroll
    for (int tj = 0; tj < 2; tj++) {
      int pxo = wx * 64 + tj * 32 + ln31;
      int y = r0 + (pxo >> 4), x = c0 + (pxo & 15);
      if (y >= H || x >= W) continue;
#pragma unroll
      for (int reg = 0; reg < 16; reg++) {
        int row = (reg & 3) + 8 * (reg >> 2) + 4 * fh;
        int co = cob + wy * 64 + ti * 32 + row;
        float vv = fmaxf(acc[ti][tj][reg] + bf[co], 0.f);
        outp[(size_t)(n * 256 + co) * HW + y * W + x] = vv;
      }
    }
}

// ---------------- K2: fused all-level projection + sigmoid + decode ----------------
__global__ __launch_bounds__(256) void proj_mega(
    const float* __restrict__ rfbase, const float* __restrict__ Wsc,
    const float* __restrict__ bsc, const float* __restrict__ Wdl,
    const float* __restrict__ bdl, const float* __restrict__ imsh,
    float* __restrict__ probs, float* __restrict__ boxes,
    int pbid0, int rfmode)
{
  __shared__ float4 wall[256 * 4];
  const int t = threadIdx.x;
  {
    int c = t;
    wall[c * 4 + 0] = make_float4(Wsc[c], Wsc[256 + c], Wsc[512 + c], Wdl[c]);
    wall[c * 4 + 1] = make_float4(Wdl[256 + c], Wdl[512 + c], Wdl[768 + c], Wdl[1024 + c]);
    wall[c * 4 + 2] = make_float4(Wdl[1280 + c], Wdl[1536 + c], Wdl[1792 + c], Wdl[2048 + c]);
    wall[c * 4 + 3] = make_float4(Wdl[2304 + c], Wdl[2560 + c], Wdl[2816 + c], 0.f);
  }
  __syncthreads();
  int pb = blockIdx.x + pbid0;
  int l = 0, poff = 0;
  if (pb >= 200) { l = 1; poff = 200; }
  if (pb >= 250) { l = 2; poff = 250; }
  if (pb >= 263) { l = 3; poff = 263; }
  if (pb >= 267) { l = 4; poff = 267; }
  const int H = 160 >> l, W = H, HW = H * W;
  int cumA = (102400 - 4 * HW) / 3;
  int cum = cumA;
  if (rfmode && l >= 1) cum -= 25600;
  const float* rf = rfbase + (size_t)512 * cum;
  const int lvl_off = 3 * cumA;
  const float sstride = (float)(4 << l);
  const float asize = (float)(32 << l);

  int idx = (pb - poff) * 256 + t;
  if (idx >= 2 * HW) return;
  int n  = idx / HW;
  int hw = idx - n * HW;
  const float* rp = rf + (size_t)n * 256 * HW + hw;
  float4 s0 = {0,0,0,0}, s1 = {0,0,0,0}, s2 = {0,0,0,0}, s3 = {0,0,0,0};
#pragma unroll 4
  for (int c = 0; c < 256; c++) {
    float v = rp[(size_t)c * HW];
    float4 w0 = wall[c*4+0], w1 = wall[c*4+1], w2 = wall[c*4+2], w3 = wall[c*4+3];
    s0.x = fmaf(v, w0.x, s0.x); s0.y = fmaf(v, w0.y, s0.y); s0.z = fmaf(v, w0.z, s0.z); s0.w = fmaf(v, w0.w, s0.w);
    s1.x = fmaf(v, w1.x, s1.x); s1.y = fmaf(v, w1.y, s1.y); s1.z = fmaf(v, w1.z, s1.z); s1.w = fmaf(v, w1.w, s1.w);
    s2.x = fmaf(v, w2.x, s2.x); s2.y = fmaf(v, w2.y, s2.y); s2.z = fmaf(v, w2.z, s2.z); s2.w = fmaf(v, w2.w, s2.w);
    s3.x = fmaf(v, w3.x, s3.x); s3.y = fmaf(v, w3.y, s3.y); s3.z = fmaf(v, w3.z, s3.z);
  }
  float imh = imsh[n * 2 + 0], imw = imsh[n * 2 + 1];
  int h = hw / W, w = hw - h * W;
  float acx = ((float)w + 0.5f) * sstride;
  float acy = ((float)h + 0.5f) * sstride;
  float sc[3]  = {s0.x + bsc[0], s0.y + bsc[1], s0.z + bsc[2]};
  float dl[12] = {s0.w + bdl[0], s1.x + bdl[1], s1.y + bdl[2],  s1.z + bdl[3],
                  s1.w + bdl[4], s2.x + bdl[5], s2.y + bdl[6],  s2.z + bdl[7],
                  s2.w + bdl[8], s3.x + bdl[9], s3.y + bdl[10], s3.z + bdl[11]};
  const float srt[3] = {0.70710678118654752440f, 1.0f, 1.41421356237309504880f};
#pragma unroll
  for (int a = 0; a < 3; a++) {
    float aw = asize / srt[a];
    float ah = asize * srt[a];
    float dx = dl[4*a+0], dy = dl[4*a+1];
    float dwv = fminf(dl[4*a+2], BBCLIP);
    float dhv = fminf(dl[4*a+3], BBCLIP);
    float cx = dx * aw + acx;
    float cy = dy * ah + acy;
    float ww = expf(dwv) * aw;
    float hh = expf(dhv) * ah;
    float x1 = cx - 0.5f * ww, y1 = cy - 0.5f * hh;
    float x2 = cx + 0.5f * ww, y2 = cy + 0.5f * hh;
    x1 = fminf(fmaxf(x1, 0.f), imw); x2 = fminf(fmaxf(x2, 0.f), imw);
    y1 = fminf(fmaxf(y1, 0.f), imh); y2 = fminf(fmaxf(y2, 0.f), imh);
    bool ok = (x2 - x1 >= 0.1f) && (y2 - y1 >= 0.1f);
    float s = sc[a];
    float p;
    if (ok) p = (s >= 0.f) ? (1.f / (1.f + expf(-s))) : (expf(s) / (1.f + expf(s)));
    else    p = -1.f;
    int o = n * TOT_PL + lvl_off + hw * 3 + a;
    probs[o] = p;
    *(float4*)&boxes[(size_t)o * 4] = make_float4(x1, y1, x2, y2);
  }
}

// ---------------- K3: single-kernel per-(img,level) top-K (4-pass radix in LDS + sort) ----------------
__global__ __launch_bounds__(1024) void topk_level(
    const float* __restrict__ probs, const float* __restrict__ boxes,
    float* __restrict__ topP, float* __restrict__ topB)
{
  const int t = threadIdx.x;
  const int inst = blockIdx.x;
  const int img = inst / 5, lvl = inst - img * 5;
  const int N = c_LN[lvl], K = c_KK[lvl];
  const int base = img * TOT_PL + c_LOFF[lvl];

  __shared__ u32 hist[256];
  __shared__ int sfx[256];
  __shared__ int sdig, sabv;
  __shared__ u64 sbuf[2048];
  __shared__ int scnt;

  u32 prefix = 0;
  int remK = K;
  const int n4 = N >> 2;
  if (N > K) {
    for (int p = 0; p < 4; p++) {
      const int shift = 24 - 8 * p;
      if (t < 256) hist[t] = 0;
      __syncthreads();
      for (int i4 = t; i4 < n4; i4 += 1024) {
        float4 p4 = *(const float4*)&probs[base + 4 * i4];
        u32 k0 = fkey(p4.x), k1 = fkey(p4.y), k2 = fkey(p4.z), k3 = fkey(p4.w);
        if (((u64)k0 >> (shift + 8)) == ((u64)prefix >> (shift + 8))) atomicAdd(&hist[(k0 >> shift) & 255], 1u);
        if (((u64)k1 >> (shift + 8)) == ((u64)prefix >> (shift + 8))) atomicAdd(&hist[(k1 >> shift) & 255], 1u);
        if (((u64)k2 >> (shift + 8)) == ((u64)prefix >> (shift + 8))) atomicAdd(&hist[(k2 >> shift) & 255], 1u);
        if (((u64)k3 >> (shift + 8)) == ((u64)prefix >> (shift + 8))) atomicAdd(&hist[(k3 >> shift) & 255], 1u);
      }
      __syncthreads();
      if (t < 256) sfx[t] = (int)hist[t];
      __syncthreads();
      for (int d = 1; d < 256; d <<= 1) {
        int v = 0;
        if (t < 256 && t + d < 256) v = sfx[t + d];
        __syncthreads();
        if (t < 256) sfx[t] += v;
        __syncthreads();
      }
      if (t < 256) {
        int above = (t < 255) ? sfx[t + 1] : 0;
        if (above < remK && sfx[t] >= remK) { sdig = t; sabv = above; }
      }
      __syncthreads();
      prefix |= ((u32)sdig) << shift;
      remK -= sabv;
      __syncthreads();
    }
  }
  const u32 V = (N <= K) ? 0u : prefix;
  if (t == 0) scnt = 0;
  __syncthreads();
  for (int i4 = t; i4 < n4; i4 += 1024) {
    float4 p4 = *(const float4*)&probs[base + 4 * i4];
    float pv[4] = {p4.x, p4.y, p4.z, p4.w};
#pragma unroll
    for (int q = 0; q < 4; q++) {
      u32 k = fkey(pv[q]);
      if (k >= V) {
        int pos = atomicAdd(&scnt, 1);
        if (pos < 2048) sbuf[pos] = ((u64)k << 17) | (u64)(131071 - (4 * i4 + q));
      }
    }
  }
  __syncthreads();
  int cntv = scnt; if (cntv > 2048) cntv = 2048;
  for (int i = t; i < 2048; i += 1024) if (i >= cntv) sbuf[i] = 0;
  bitonic_desc<2048, 1024>(sbuf, t);
  for (int r = t; r < 1000; r += 1024) {
    if (r < K) {
      u64 k = sbuf[r];
      int idx = 131071 - (int)(k & 0x1FFFF);
      topP[inst * 1000 + r] = probs[base + idx];
      *(float4*)&topB[(size_t)(inst * 1000 + r) * 4] = *(const float4*)&boxes[(size_t)(base + idx) * 4];
    } else {
      topP[inst * 1000 + r] = -1.f;
      *(float4*)&topB[(size_t)(inst * 1000 + r) * 4] = make_float4(0, 0, 0, 0);
    }
  }
}

// ---------------- K4a: IoU>thresh bitmask build ----------------
__global__ __launch_bounds__(256) void nms_mask(
    const float* __restrict__ topB, u64* __restrict__ mask)
{
  __shared__ float bx1[1000], by1[1000], bx2[1000], by2[1000], bar[1000];
  const int t = threadIdx.x;
  const int inst = blockIdx.y;
  for (int r = t; r < 1000; r += 256) {
    float4 b = *(const float4*)&topB[(size_t)(inst * 1000 + r) * 4];
    bx1[r] = b.x; by1[r] = b.y; bx2[r] = b.z; by2[r] = b.w;
    bar[r] = (b.z - b.x) * (b.w - b.y);
  }
  __syncthreads();
  const int i = blockIdx.x * 16 + (t >> 4);
  const int w = t & 15;
  if (i >= 1000) return;
  u64 m = 0;
  const int jbase = w * 64;
  if (jbase + 63 > i) {
    float xi1 = bx1[i], yi1 = by1[i], xi2 = bx2[i], yi2 = by2[i], ai = bar[i];
#pragma unroll 4
    for (int b = 0; b < 64; b++) {
      int j = jbase + b;
      if (j > i && j < 1000) {
        float ww = fminf(xi2, bx2[j]) - fmaxf(xi1, bx1[j]); ww = fmaxf(ww, 0.f);
        float hh = fminf(yi2, by2[j]) - fmaxf(yi1, by1[j]); hh = fmaxf(hh, 0.f);
        float inter = ww * hh;
        float iou = inter / (ai + bar[j] - inter + 1e-9f);
        if (iou > 0.7f) m |= 1ull << b;
      }
    }
  }
  mask[(size_t)(inst * 1000 + i) * 16 + w] = m;
}

// ---------------- K4b: sequential suppression scan (1 wave) + ordered compaction ----------------
__global__ __launch_bounds__(256) void nms_scan(
    const float* __restrict__ topP, const float* __restrict__ topB,
    const u64* __restrict__ mask,
    float* __restrict__ perP, float* __restrict__ perB)
{
  const int t = threadIdx.x;
  const int inst = blockIdx.x;
  const int lvl = inst % 5;
  const int K = c_KK[lvl];
  __shared__ float PPl[1000];
  __shared__ u64 SUPL[16];
  __shared__ int scan[256];
  for (int r = t; r < 1000; r += 256) PPl[r] = topP[inst * 1000 + r];
  __syncthreads();

  if (t < 64) {
    const bool ln16 = t < 16;
    const u64* mrow = mask + (size_t)inst * 16000;
    u64 supp = 0;
    u64 buf[16];
#pragma unroll
    for (int d = 0; d < 16; d++) buf[d] = (ln16 && d < K) ? mrow[d * 16 + t] : 0;
    for (int ib = 0; ib < 1000; ib += 16) {
#pragma unroll
      for (int q = 0; q < 16; q++) {
        int i = ib + q;
        if (i < K) {
          u64 sw = __shfl(supp, i >> 6);
          bool sbit = (sw >> (i & 63)) & 1;
          bool keep = (!sbit) && (PPl[i] > 0.f);
          if (keep && ln16) supp |= buf[q];
          int nx = i + 16;
          buf[q] = (ln16 && nx < K) ? mrow[(size_t)nx * 16 + t] : 0;
        }
      }
      if (ib + 16 >= K) break;
    }
    if (ln16) SUPL[t] = supp;
  }
  __syncthreads();

  bool kf[4]; int cntl = 0;
#pragma unroll
  for (int q = 0; q < 4; q++) {
    int r = t * 4 + q;
    bool k = (r < K) && (PPl[r] > 0.f) && !((SUPL[r >> 6] >> (r & 63)) & 1);
    kf[q] = k; cntl += k ? 1 : 0;
  }
  scan[t] = cntl; __syncthreads();
  for (int d = 1; d < 256; d <<= 1) {
    int v = (t >= d) ? scan[t - d] : 0;
    __syncthreads();
    scan[t] += v;
    __syncthreads();
  }
  int pos = (t == 0) ? 0 : scan[t - 1];
  int tot = scan[255];
#pragma unroll
  for (int q = 0; q < 4; q++) {
    int r = t * 4 + q;
    if (r < K && kf[q]) {
      if (pos < 300) {
        perP[inst * 300 + pos] = PPl[r];
        *(float4*)&perB[(size_t)(inst * 300 + pos) * 4] = *(const float4*)&topB[(size_t)(inst * 1000 + r) * 4];
      }
      pos++;
    }
  }
  int start = tot < 300 ? tot : 300;
  for (int r2 = start + t; r2 < 300; r2 += 256) {
    perP[inst * 300 + r2] = -1.f;
    *(float4*)&perB[(size_t)(inst * 300 + r2) * 4] = make_float4(0, 0, 0, 0);
  }
}

// ---------------- K5: global top-300 over 1500, write output + n ----------------
__global__ __launch_bounds__(256) void final_topk(
    const float* __restrict__ perP, const float* __restrict__ perB,
    float* __restrict__ out, float* __restrict__ nout)
{
  const int t = threadIdx.x;
  const int img = blockIdx.x;
  __shared__ u64 sb[2048];
  __shared__ int ncnt;
  for (int i = t; i < 2048; i += 256) {
    u64 k = 0;
    if (i < 1500) k = ((u64)fkey(perP[img * 1500 + i]) << 11) | (u64)(2047 - i);
    sb[i] = k;
  }
  if (t == 0) ncnt = 0;
  bitonic_desc<2048, 256>(sb, t);
  int localn = 0;
  for (int r = t; r < 300; r += 256) {
    u64 k = sb[r];
    int idx = 2047 - (int)(k & 0x7FF);
    float p = perP[img * 1500 + idx];
    bool valid = p > 0.f;
    float4 b = make_float4(0, 0, 0, 0);
    if (valid) b = *(const float4*)&perB[(size_t)(img * 1500 + idx) * 4];
    float* o = out + (size_t)img * 1500 + (size_t)r * 5;
    o[0] = b.x; o[1] = b.y; o[2] = b.z; o[3] = b.w;
    o[4] = valid ? p : 0.f;
    if (valid) localn++;
  }
  atomicAdd(&ncnt, localn);
  __syncthreads();
  if (t == 0) nout[img] = (float)ncnt;
}

// ---------------- launch ----------------
extern "C" void kernel_launch(void* const* d_in, const int* in_sizes, int n_in,
                              void* d_out, int out_size, void* d_ws, size_t ws_size,
                              hipStream_t stream) {
  const float* f0   = (const float*)d_in[0];
  const float* f1   = (const float*)d_in[1];
  const float* f2   = (const float*)d_in[2];
  const float* f3   = (const float*)d_in[3];
  const float* f4   = (const float*)d_in[4];
  const float* imsh = (const float*)d_in[5];
  const float* Wf   = (const float*)d_in[6];
  const float* bfv  = (const float*)d_in[7];
  const float* Wsc  = (const float*)d_in[8];
  const float* bsc  = (const float*)d_in[9];
  const float* Wdl  = (const float*)d_in[10];
  const float* bdl  = (const float*)d_in[11];

  const size_t rfF_fused = 17459200;   // 512 * 34100 (all levels coexist)
  const size_t rfF_seq   = 13107200;   // L0 only; L1-4 shifted down after proj(L0)
  const size_t tailF     = 204600 + 818400 + 10000 + 40000 + 3000 + 12000 + 884736;
  const bool fused = (ws_size >= (rfF_fused + tailF) * 4);
  const size_t rfF = fused ? rfF_fused : rfF_seq;

  float* ws     = (float*)d_ws;
  float* rfbuf  = ws;
  u64*  mask    = (u64*)d_ws;                // overlay: used only after proj done
  float* probs  = rfbuf + rfF;               // 204,600
  float* boxesb = probs + 204600;            // 818,400
  float* topP   = boxesb + 818400;           // 10,000
  float* topB   = topP + 10000;              // 40,000
  float* perP   = topB + 40000;              // 3,000
  float* perB   = perP + 3000;               // 12,000
  u32*  Wt32    = (u32*)(perB + 12000);      // 884,736 u32

  prep_weights<<<2304, 256, 0, stream>>>(Wf, (unsigned short*)Wt32);

  if (fused) {
    conv_mega<<<1092, 256, 0, stream>>>(f0, f1, f2, f3, f4, Wt32, bfv, rfbuf, 0, 0);
    proj_mega<<<268, 256, 0, stream>>>(rfbuf, Wsc, bsc, Wdl, bdl, imsh, probs, boxesb, 0, 0);
  } else {
    conv_mega<<<800, 256, 0, stream>>>(f0, f1, f2, f3, f4, Wt32, bfv, rfbuf, 0, 1);
    proj_mega<<<200, 256, 0, stream>>>(rfbuf, Wsc, bsc, Wdl, bdl, imsh, probs, boxesb, 0, 1);
    conv_mega<<<292, 256, 0, stream>>>(f0, f1, f2, f3, f4, Wt32, bfv, rfbuf, 800, 1);
    proj_mega<<<68, 256, 0, stream>>>(rfbuf, Wsc, bsc, Wdl, bdl, imsh, probs, boxesb, 200, 1);
  }
  topk_level<<<10, 1024, 0, stream>>>(probs, boxesb, topP, topB);
  {
    dim3 gm(63, 10);
    nms_mask<<<gm, 256, 0, stream>>>(topB, mask);
  }
  nms_scan<<<10, 256, 0, stream>>>(topP, topB, mask, perP, perB);
  final_topk<<<2, 256, 0, stream>>>(perP, perB, (float*)d_out, (float*)d_out + 3000);
}

// Round 8
// 1020.553 us; speedup vs baseline: 1.4242x; 1.4242x over previous
//
#include <hip/hip_runtime.h>
#include <stdint.h>

typedef unsigned long long u64;
typedef unsigned int u32;
using short8  = __attribute__((ext_vector_type(8))) short;
using f32x16  = __attribute__((ext_vector_type(16))) float;

__constant__ int c_LN[5]   = {76800, 19200, 4800, 1200, 300}; // H*H*3 per level
__constant__ int c_LOFF[5] = {0, 76800, 96000, 100800, 102000};
__constant__ int c_KK[5]   = {1000, 1000, 1000, 1000, 300};   // k1 = min(1000, N)

#define TOT_PL 102300
#define BBCLIP 4.1351665567423560f

__device__ __forceinline__ u32 fkey(float f) {
  u32 b = __float_as_uint(f);
  return b ^ (u32)(((int)b >> 31) | 0x80000000u);
}

template<int NELEM, int NTHR>
__device__ __forceinline__ void bitonic_desc(u64* sb, int t) {
  constexpr int PAIRS = NELEM / 2;
  for (int size = 2; size <= NELEM; size <<= 1) {
    for (int stride = size >> 1; stride > 0; stride >>= 1) {
      __syncthreads();
      for (int i = t; i < PAIRS; i += NTHR) {
        int pos = 2 * i - (i & (stride - 1));
        u64 a = sb[pos], b = sb[pos + stride];
        bool desc = ((pos & size) == 0);
        if (desc ? (a < b) : (a > b)) { sb[pos] = b; sb[pos + stride] = a; }
      }
    }
  }
  __syncthreads();
}

// ---------------- K0: pre-transpose weights, 3-way bf16 split ----------------
// chunk ca = tap*16 + g covers k [16ca,16ca+16): ci = g*16 + kloc, kloc = half*8 + j.
// Wt u16 layout: slice = (ca*6 + split*2 + half); within slice: co granule of 8 u16.
__global__ __launch_bounds__(256) void prep_weights(
    const float* __restrict__ Wf, unsigned short* __restrict__ Wt)
{
  int idx = blockIdx.x * 256 + threadIdx.x;   // E = 2304*256
  if (idx >= 589824) return;
  int co = idx & 255;
  int k2 = idx >> 8;            // 0..2303
  int chunk = k2 >> 4, kloc = k2 & 15;
  int tap = chunk / 16, g = chunk & 15;
  int ci = (g << 4) + kloc;
  float v = Wf[co * 2304 + ci * 9 + tap];
  u32 u0 = __float_as_uint(v) & 0xFFFF0000u;
  float r1 = v - __uint_as_float(u0);
  u32 u1 = __float_as_uint(r1) & 0xFFFF0000u;
  float r2 = r1 - __uint_as_float(u1);
  u32 u2 = __float_as_uint(r2) & 0xFFFF0000u;
  int half = kloc >> 3, j = kloc & 7;
  int base = (chunk * 6 + half) * 2048 + co * 8 + j;   // +4096 u16 per split
  Wt[base]          = (unsigned short)(u0 >> 16);
  Wt[base + 4096]   = (unsigned short)(u1 >> 16);
  Wt[base + 8192]   = (unsigned short)(u2 >> 16);
}

// ---------------- K1: fused all-level 3x3 conv via MFMA ----------------
// 128co x 128px tile. Single haloP buffer (restaged once per ci-block, inline,
// no long-lived prefetch regs). A-chunks cooperatively staged into DOUBLE-
// buffered LDS: next chunk's global loads issued before this tap's MFMA,
// written to LDS after -> barriers order LDS only, never exposed vm latency.
__global__ __launch_bounds__(256, 3) void conv_mega(
    const float* __restrict__ f0, const float* __restrict__ f1,
    const float* __restrict__ f2, const float* __restrict__ f3,
    const float* __restrict__ f4,
    const u32* __restrict__ Wt32, const float* __restrict__ bf,
    float* __restrict__ rfbase, int bid0, int rfmode)
{
  __shared__ u32   haloP[4800];      // 19.2 KB
  __shared__ uint4 Abuf[2][768];     // 24.6 KB
  const int t = threadIdx.x;
  int b = blockIdx.x + bid0;
  int l = 0, boff = 0;
  if (b >= 800)  { l = 1; boff = 800; }
  if (b >= 1000) { l = 2; boff = 1000; }
  if (b >= 1060) { l = 3; boff = 1060; }
  if (b >= 1084) { l = 4; boff = 1084; }
  const int H = 160 >> l, W = H, HW = H * W;
  const int tiles_x = (W + 15) >> 4;
  const int T = tiles_x * ((H + 7) >> 3);
  int local = b - boff;
  int tile = local % T, rest = local / T;
  const int cob = (rest & 1) * 128;
  const int n = rest >> 1;
  int tx = tile % tiles_x, ty = tile / tiles_x;
  const int c0 = tx * 16, r0 = ty * 8;
  const float* feat = (l == 0) ? f0 : (l == 1) ? f1 : (l == 2) ? f2 : (l == 3) ? f3 : f4;
  const float* featN = feat + (size_t)n * 256 * HW;
  int cum = (102400 - 4 * HW) / 3;
  if (rfmode && l >= 1) cum -= 25600;
  float* outp = rfbase + (size_t)512 * cum;
  const uint4* Wtq = (const uint4*)Wt32;

  const int lane = t & 63;
  const int wave = t >> 6;
  const int wy = wave >> 1, wx = wave & 1;
  const int fh = lane >> 5;
  const int ln31 = lane & 31;

  // ---- halo staging mapping (fixed per thread) ----
  int offsp[7], ostore[7], cio[7];
  bool vOK[7], sOK[7];
#pragma unroll
  for (int i = 0; i < 7; i++) {
    int e2 = t + i * 256;
    sOK[i] = (e2 < 1600);
    int pp = e2 & 3, q = e2 >> 2;
    int half = q / 200, rem = q - half * 200;
    int y = rem / 20, x = rem - y * 20;
    int gy = r0 + y - 1, gx = c0 + x - 1;
    bool val = sOK[i] && (x < 18) && ((unsigned)gy < (unsigned)H) && ((unsigned)gx < (unsigned)W);
    vOK[i] = val;
    offsp[i] = val ? (gy * W + gx) : 0;
    cio[i] = half * 8 + pp * 2;
    ostore[i] = half * 800 + rem * 4 + pp;
  }

  f32x16 acc[2][2];
#pragma unroll
  for (int i = 0; i < 2; i++)
#pragma unroll
    for (int j = 0; j < 2; j++)
#pragma unroll
      for (int e = 0; e < 16; e++) acc[i][j][e] = 0.f;

  // ---- prologue: stage halo(g=0) and A(chunk 0) into Abuf[0] ----
  {
    const float* fgn = featN;
#pragma unroll
    for (int i = 0; i < 7; i++) {
      if (sOK[i]) {
        const float* p = fgn + (size_t)cio[i] * HW + offsp[i];
        float a = vOK[i] ? p[0] : 0.f;
        float bv = vOK[i] ? p[HW] : 0.f;
        u32 a0 = __float_as_uint(a) & 0xFFFF0000u;
        float ar1 = a - __uint_as_float(a0);
        u32 a1 = __float_as_uint(ar1) & 0xFFFF0000u;
        float ar2 = ar1 - __uint_as_float(a1);
        u32 a2 = __float_as_uint(ar2) & 0xFFFF0000u;
        u32 b0 = __float_as_uint(bv) & 0xFFFF0000u;
        float br1 = bv - __uint_as_float(b0);
        u32 b1 = __float_as_uint(br1) & 0xFFFF0000u;
        float br2 = br1 - __uint_as_float(b1);
        u32 b2 = __float_as_uint(br2) & 0xFFFF0000u;
        int o = ostore[i];
        haloP[o]        = (a0 >> 16) | b0;
        haloP[o + 1600] = (a1 >> 16) | b1;
        haloP[o + 3200] = (a2 >> 16) | b2;
      }
    }
#pragma unroll
    for (int q = 0; q < 3; q++) {
      int g2 = t + q * 256;
      Abuf[0][g2] = Wtq[(size_t)((g2 >> 7)) * 256 + cob + (g2 & 127)];  // ca=0
    }
  }
  __syncthreads();

  int par = 0;
  for (int g = 0; g < 16; g++) {
    for (int tap = 0; tap < 9; tap++) {
      const bool hasNext = !(tap == 8 && g == 15);
      const int nca = (tap < 8) ? ((tap + 1) * 16 + g) : (g + 1);
      // issue next A-chunk global loads (consumed after MFMA)
      uint4 aw0, aw1, aw2;
      if (hasNext) {
        aw0 = Wtq[(size_t)(nca * 6 + ((t + 0) >> 7)) * 256 + cob + ((t + 0) & 127)];
        aw1 = Wtq[(size_t)(nca * 6 + ((t + 256) >> 7)) * 256 + cob + ((t + 256) & 127)];
        aw2 = Wtq[(size_t)(nca * 6 + ((t + 512) >> 7)) * 256 + cob + ((t + 512) & 127)];
      }
      // fragment loads from LDS
      const int tdy = tap / 3, tdx = tap - tdy * 3;
      short8 aT[3][2], bT[3][2];
#pragma unroll
      for (int sp = 0; sp < 3; sp++) {
#pragma unroll
        for (int ti = 0; ti < 2; ti++)
          aT[sp][ti] = *(const short8*)&Abuf[par][(sp * 2 + fh) * 128 + wy * 64 + ti * 32 + ln31];
#pragma unroll
        for (int tj = 0; tj < 2; tj++) {
          int px = wx * 64 + tj * 32 + ln31;
          int pos = ((px >> 4) + tdy) * 20 + (px & 15) + tdx;
          bT[sp][tj] = *(const short8*)&haloP[(sp * 2 + fh) * 800 + pos * 4];
        }
      }
#pragma unroll
      for (int ti = 0; ti < 2; ti++)
#pragma unroll
        for (int tj = 0; tj < 2; tj++) {
          acc[ti][tj] = __builtin_amdgcn_mfma_f32_32x32x16_bf16(aT[1][ti], bT[1][tj], acc[ti][tj], 0, 0, 0);
          acc[ti][tj] = __builtin_amdgcn_mfma_f32_32x32x16_bf16(aT[0][ti], bT[2][tj], acc[ti][tj], 0, 0, 0);
          acc[ti][tj] = __builtin_amdgcn_mfma_f32_32x32x16_bf16(aT[2][ti], bT[0][tj], acc[ti][tj], 0, 0, 0);
          acc[ti][tj] = __builtin_amdgcn_mfma_f32_32x32x16_bf16(aT[0][ti], bT[1][tj], acc[ti][tj], 0, 0, 0);
          acc[ti][tj] = __builtin_amdgcn_mfma_f32_32x32x16_bf16(aT[1][ti], bT[0][tj], acc[ti][tj], 0, 0, 0);
          acc[ti][tj] = __builtin_amdgcn_mfma_f32_32x32x16_bf16(aT[0][ti], bT[0][tj], acc[ti][tj], 0, 0, 0);
        }
      // restage halo for g+1 (all waves finished reading haloP(g) at this tap)
      if (tap == 8 && g < 15) {
        __syncthreads();
        const float* fgn = featN + (size_t)((g + 1) << 4) * HW;
#pragma unroll
        for (int i = 0; i < 7; i++) {
          if (sOK[i]) {
            const float* p = fgn + (size_t)cio[i] * HW + offsp[i];
            float a = vOK[i] ? p[0] : 0.f;
            float bv = vOK[i] ? p[HW] : 0.f;
            u32 a0 = __float_as_uint(a) & 0xFFFF0000u;
            float ar1 = a - __uint_as_float(a0);
            u32 a1 = __float_as_uint(ar1) & 0xFFFF0000u;
            float ar2 = ar1 - __uint_as_float(a1);
            u32 a2 = __float_as_uint(ar2) & 0xFFFF0000u;
            u32 b0 = __float_as_uint(bv) & 0xFFFF0000u;
            float br1 = bv - __uint_as_float(b0);
            u32 b1 = __float_as_uint(br1) & 0xFFFF0000u;
            float br2 = br1 - __uint_as_float(b1);
            u32 b2 = __float_as_uint(br2) & 0xFFFF0000u;
            int o = ostore[i];
            haloP[o]        = (a0 >> 16) | b0;
            haloP[o + 1600] = (a1 >> 16) | b1;
            haloP[o + 3200] = (a2 >> 16) | b2;
          }
        }
      }
      // commit next A-chunk into the other buffer (vm wait lands here, post-MFMA)
      if (hasNext) {
        Abuf[par ^ 1][t]       = aw0;
        Abuf[par ^ 1][t + 256] = aw1;
        Abuf[par ^ 1][t + 512] = aw2;
      }
      __syncthreads();
      par ^= 1;
    }
  }

  // ---- epilogue: bias + relu, write rf ----
#pragma unroll
  for (int ti = 0; ti < 2; ti++)
#pragma unroll
    for (int tj = 0; tj < 2; tj++) {
      int pxo = wx * 64 + tj * 32 + ln31;
      int y = r0 + (pxo >> 4), x = c0 + (pxo & 15);
      if (y >= H || x >= W) continue;
#pragma unroll
      for (int reg = 0; reg < 16; reg++) {
        int row = (reg & 3) + 8 * (reg >> 2) + 4 * fh;
        int co = cob + wy * 64 + ti * 32 + row;
        float vv = fmaxf(acc[ti][tj][reg] + bf[co], 0.f);
        outp[(size_t)(n * 256 + co) * HW + y * W + x] = vv;
      }
    }
}

// ---------------- K2: fused all-level projection + sigmoid + decode ----------------
__global__ __launch_bounds__(256) void proj_mega(
    const float* __restrict__ rfbase, const float* __restrict__ Wsc,
    const float* __restrict__ bsc, const float* __restrict__ Wdl,
    const float* __restrict__ bdl, const float* __restrict__ imsh,
    float* __restrict__ probs, float* __restrict__ boxes,
    int pbid0, int rfmode)
{
  __shared__ float4 wall[256 * 4];
  const int t = threadIdx.x;
  {
    int c = t;
    wall[c * 4 + 0] = make_float4(Wsc[c], Wsc[256 + c], Wsc[512 + c], Wdl[c]);
    wall[c * 4 + 1] = make_float4(Wdl[256 + c], Wdl[512 + c], Wdl[768 + c], Wdl[1024 + c]);
    wall[c * 4 + 2] = make_float4(Wdl[1280 + c], Wdl[1536 + c], Wdl[1792 + c], Wdl[2048 + c]);
    wall[c * 4 + 3] = make_float4(Wdl[2304 + c], Wdl[2560 + c], Wdl[2816 + c], 0.f);
  }
  __syncthreads();
  int pb = blockIdx.x + pbid0;
  int l = 0, poff = 0;
  if (pb >= 200) { l = 1; poff = 200; }
  if (pb >= 250) { l = 2; poff = 250; }
  if (pb >= 263) { l = 3; poff = 263; }
  if (pb >= 267) { l = 4; poff = 267; }
  const int H = 160 >> l, W = H, HW = H * W;
  int cumA = (102400 - 4 * HW) / 3;
  int cum = cumA;
  if (rfmode && l >= 1) cum -= 25600;
  const float* rf = rfbase + (size_t)512 * cum;
  const int lvl_off = 3 * cumA;
  const float sstride = (float)(4 << l);
  const float asize = (float)(32 << l);

  int idx = (pb - poff) * 256 + t;
  if (idx >= 2 * HW) return;
  int n  = idx / HW;
  int hw = idx - n * HW;
  const float* rp = rf + (size_t)n * 256 * HW + hw;
  float4 s0 = {0,0,0,0}, s1 = {0,0,0,0}, s2 = {0,0,0,0}, s3 = {0,0,0,0};
#pragma unroll 4
  for (int c = 0; c < 256; c++) {
    float v = rp[(size_t)c * HW];
    float4 w0 = wall[c*4+0], w1 = wall[c*4+1], w2 = wall[c*4+2], w3 = wall[c*4+3];
    s0.x = fmaf(v, w0.x, s0.x); s0.y = fmaf(v, w0.y, s0.y); s0.z = fmaf(v, w0.z, s0.z); s0.w = fmaf(v, w0.w, s0.w);
    s1.x = fmaf(v, w1.x, s1.x); s1.y = fmaf(v, w1.y, s1.y); s1.z = fmaf(v, w1.z, s1.z); s1.w = fmaf(v, w1.w, s1.w);
    s2.x = fmaf(v, w2.x, s2.x); s2.y = fmaf(v, w2.y, s2.y); s2.z = fmaf(v, w2.z, s2.z); s2.w = fmaf(v, w2.w, s2.w);
    s3.x = fmaf(v, w3.x, s3.x); s3.y = fmaf(v, w3.y, s3.y); s3.z = fmaf(v, w3.z, s3.z);
  }
  float imh = imsh[n * 2 + 0], imw = imsh[n * 2 + 1];
  int h = hw / W, w = hw - h * W;
  float acx = ((float)w + 0.5f) * sstride;
  float acy = ((float)h + 0.5f) * sstride;
  float sc[3]  = {s0.x + bsc[0], s0.y + bsc[1], s0.z + bsc[2]};
  float dl[12] = {s0.w + bdl[0], s1.x + bdl[1], s1.y + bdl[2],  s1.z + bdl[3],
                  s1.w + bdl[4], s2.x + bdl[5], s2.y + bdl[6],  s2.z + bdl[7],
                  s2.w + bdl[8], s3.x + bdl[9], s3.y + bdl[10], s3.z + bdl[11]};
  const float srt[3] = {0.70710678118654752440f, 1.0f, 1.41421356237309504880f};
#pragma unroll
  for (int a = 0; a < 3; a++) {
    float aw = asize / srt[a];
    float ah = asize * srt[a];
    float dx = dl[4*a+0], dy = dl[4*a+1];
    float dwv = fminf(dl[4*a+2], BBCLIP);
    float dhv = fminf(dl[4*a+3], BBCLIP);
    float cx = dx * aw + acx;
    float cy = dy * ah + acy;
    float ww = expf(dwv) * aw;
    float hh = expf(dhv) * ah;
    float x1 = cx - 0.5f * ww, y1 = cy - 0.5f * hh;
    float x2 = cx + 0.5f * ww, y2 = cy + 0.5f * hh;
    x1 = fminf(fmaxf(x1, 0.f), imw); x2 = fminf(fmaxf(x2, 0.f), imw);
    y1 = fminf(fmaxf(y1, 0.f), imh); y2 = fminf(fmaxf(y2, 0.f), imh);
    bool ok = (x2 - x1 >= 0.1f) && (y2 - y1 >= 0.1f);
    float s = sc[a];
    float p;
    if (ok) p = (s >= 0.f) ? (1.f / (1.f + expf(-s))) : (expf(s) / (1.f + expf(s)));
    else    p = -1.f;
    int o = n * TOT_PL + lvl_off + hw * 3 + a;
    probs[o] = p;
    *(float4*)&boxes[(size_t)o * 4] = make_float4(x1, y1, x2, y2);
  }
}

// ---------------- K3: per-(img,level) top-K: 4-pass radix (per-wave hists) + sort ----------------
__global__ __launch_bounds__(1024) void topk_level(
    const float* __restrict__ probs, const float* __restrict__ boxes,
    float* __restrict__ topP, float* __restrict__ topB)
{
  const int t = threadIdx.x;
  const int inst = blockIdx.x;
  const int img = inst / 5, lvl = inst - img * 5;
  const int N = c_LN[lvl], K = c_KK[lvl];
  const int base = img * TOT_PL + c_LOFF[lvl];
  const int wid = t >> 6;

  __shared__ u32 whist[16 * 256];   // per-wave histograms: <=64-way atomic contention
  __shared__ int sfx[256];
  __shared__ int sdig, sabv;
  __shared__ u64 sbuf[2048];
  __shared__ int scnt;

  u32 prefix = 0;
  int remK = K;
  const int n4 = N >> 2;
  if (N > K) {
    for (int p = 0; p < 4; p++) {
      const int shift = 24 - 8 * p;
      for (int i = t; i < 4096; i += 1024) whist[i] = 0;
      __syncthreads();
      u32* wh = &whist[wid * 256];
      for (int i4 = t; i4 < n4; i4 += 1024) {
        float4 p4 = *(const float4*)&probs[base + 4 * i4];
        u32 k0 = fkey(p4.x), k1 = fkey(p4.y), k2 = fkey(p4.z), k3 = fkey(p4.w);
        if (((u64)k0 >> (shift + 8)) == ((u64)prefix >> (shift + 8))) atomicAdd(&wh[(k0 >> shift) & 255], 1u);
        if (((u64)k1 >> (shift + 8)) == ((u64)prefix >> (shift + 8))) atomicAdd(&wh[(k1 >> shift) & 255], 1u);
        if (((u64)k2 >> (shift + 8)) == ((u64)prefix >> (shift + 8))) atomicAdd(&wh[(k2 >> shift) & 255], 1u);
        if (((u64)k3 >> (shift + 8)) == ((u64)prefix >> (shift + 8))) atomicAdd(&wh[(k3 >> shift) & 255], 1u);
      }
      __syncthreads();
      if (t < 256) {
        int s = 0;
#pragma unroll
        for (int w = 0; w < 16; w++) s += (int)whist[w * 256 + t];
        sfx[t] = s;
      }
      __syncthreads();
      for (int d = 1; d < 256; d <<= 1) {
        int v = 0;
        if (t < 256 && t + d < 256) v = sfx[t + d];
        __syncthreads();
        if (t < 256) sfx[t] += v;
        __syncthreads();
      }
      if (t < 256) {
        int above = (t < 255) ? sfx[t + 1] : 0;
        if (above < remK && sfx[t] >= remK) { sdig = t; sabv = above; }
      }
      __syncthreads();
      prefix |= ((u32)sdig) << shift;
      remK -= sabv;
      __syncthreads();
    }
  }
  const u32 V = (N <= K) ? 0u : prefix;
  if (t == 0) scnt = 0;
  __syncthreads();
  for (int i4 = t; i4 < n4; i4 += 1024) {
    float4 p4 = *(const float4*)&probs[base + 4 * i4];
    float pv[4] = {p4.x, p4.y, p4.z, p4.w};
#pragma unroll
    for (int q = 0; q < 4; q++) {
      u32 k = fkey(pv[q]);
      if (k >= V) {
        int pos = atomicAdd(&scnt, 1);
        if (pos < 2048) sbuf[pos] = ((u64)k << 17) | (u64)(131071 - (4 * i4 + q));
      }
    }
  }
  __syncthreads();
  int cntv = scnt; if (cntv > 2048) cntv = 2048;
  for (int i = t; i < 2048; i += 1024) if (i >= cntv) sbuf[i] = 0;
  bitonic_desc<2048, 1024>(sbuf, t);
  for (int r = t; r < 1000; r += 1024) {
    if (r < K) {
      u64 k = sbuf[r];
      int idx = 131071 - (int)(k & 0x1FFFF);
      topP[inst * 1000 + r] = probs[base + idx];
      *(float4*)&topB[(size_t)(inst * 1000 + r) * 4] = *(const float4*)&boxes[(size_t)(base + idx) * 4];
    } else {
      topP[inst * 1000 + r] = -1.f;
      *(float4*)&topB[(size_t)(inst * 1000 + r) * 4] = make_float4(0, 0, 0, 0);
    }
  }
}

// ---------------- K4a: IoU>thresh bitmask build ----------------
__global__ __launch_bounds__(256) void nms_mask(
    const float* __restrict__ topB, u64* __restrict__ mask)
{
  __shared__ float bx1[1000], by1[1000], bx2[1000], by2[1000], bar[1000];
  const int t = threadIdx.x;
  const int inst = blockIdx.y;
  for (int r = t; r < 1000; r += 256) {
    float4 b = *(const float4*)&topB[(size_t)(inst * 1000 + r) * 4];
    bx1[r] = b.x; by1[r] = b.y; bx2[r] = b.z; by2[r] = b.w;
    bar[r] = (b.z - b.x) * (b.w - b.y);
  }
  __syncthreads();
  const int i = blockIdx.x * 16 + (t >> 4);
  const int w = t & 15;
  if (i >= 1000) return;
  u64 m = 0;
  const int jbase = w * 64;
  if (jbase + 63 > i) {
    float xi1 = bx1[i], yi1 = by1[i], xi2 = bx2[i], yi2 = by2[i], ai = bar[i];
#pragma unroll 4
    for (int b = 0; b < 64; b++) {
      int j = jbase + b;
      if (j > i && j < 1000) {
        float ww = fminf(xi2, bx2[j]) - fmaxf(xi1, bx1[j]); ww = fmaxf(ww, 0.f);
        float hh = fminf(yi2, by2[j]) - fmaxf(yi1, by1[j]); hh = fmaxf(hh, 0.f);
        float inter = ww * hh;
        float iou = inter / (ai + bar[j] - inter + 1e-9f);
        if (iou > 0.7f) m |= 1ull << b;
      }
    }
  }
  mask[(size_t)(inst * 1000 + i) * 16 + w] = m;
}

// ---------------- K4b: sequential suppression scan (1 wave) + ordered compaction ----------------
__global__ __launch_bounds__(256) void nms_scan(
    const float* __restrict__ topP, const float* __restrict__ topB,
    const u64* __restrict__ mask,
    float* __restrict__ perP, float* __restrict__ perB)
{
  const int t = threadIdx.x;
  const int inst = blockIdx.x;
  const int lvl = inst % 5;
  const int K = c_KK[lvl];
  __shared__ float PPl[1000];
  __shared__ u64 SUPL[16];
  __shared__ int scan[256];
  for (int r = t; r < 1000; r += 256) PPl[r] = topP[inst * 1000 + r];
  __syncthreads();

  if (t < 64) {
    const bool ln16 = t < 16;
    const u64* mrow = mask + (size_t)inst * 16000;
    u64 supp = 0;
    u64 buf[16];
#pragma unroll
    for (int d = 0; d < 16; d++) buf[d] = (ln16 && d < K) ? mrow[d * 16 + t] : 0;
    for (int ib = 0; ib < 1000; ib += 16) {
#pragma unroll
      for (int q = 0; q < 16; q++) {
        int i = ib + q;
        if (i < K) {
          u64 sw = __shfl(supp, i >> 6);
          bool sbit = (sw >> (i & 63)) & 1;
          bool keep = (!sbit) && (PPl[i] > 0.f);
          if (keep && ln16) supp |= buf[q];
          int nx = i + 16;
          buf[q] = (ln16 && nx < K) ? mrow[(size_t)nx * 16 + t] : 0;
        }
      }
      if (ib + 16 >= K) break;
    }
    if (ln16) SUPL[t] = supp;
  }
  __syncthreads();

  bool kf[4]; int cntl = 0;
#pragma unroll
  for (int q = 0; q < 4; q++) {
    int r = t * 4 + q;
    bool k = (r < K) && (PPl[r] > 0.f) && !((SUPL[r >> 6] >> (r & 63)) & 1);
    kf[q] = k; cntl += k ? 1 : 0;
  }
  scan[t] = cntl; __syncthreads();
  for (int d = 1; d < 256; d <<= 1) {
    int v = (t >= d) ? scan[t - d] : 0;
    __syncthreads();
    scan[t] += v;
    __syncthreads();
  }
  int pos = (t == 0) ? 0 : scan[t - 1];
  int tot = scan[255];
#pragma unroll
  for (int q = 0; q < 4; q++) {
    int r = t * 4 + q;
    if (r < K && kf[q]) {
      if (pos < 300) {
        perP[inst * 300 + pos] = PPl[r];
        *(float4*)&perB[(size_t)(inst * 300 + pos) * 4] = *(const float4*)&topB[(size_t)(inst * 1000 + r) * 4];
      }
      pos++;
    }
  }
  int start = tot < 300 ? tot : 300;
  for (int r2 = start + t; r2 < 300; r2 += 256) {
    perP[inst * 300 + r2] = -1.f;
    *(float4*)&perB[(size_t)(inst * 300 + r2) * 4] = make_float4(0, 0, 0, 0);
  }
}

// ---------------- K5: global top-300 over 1500, write output + n ----------------
__global__ __launch_bounds__(256) void final_topk(
    const float* __restrict__ perP, const float* __restrict__ perB,
    float* __restrict__ out, float* __restrict__ nout)
{
  const int t = threadIdx.x;
  const int img = blockIdx.x;
  __shared__ u64 sb[2048];
  __shared__ int ncnt;
  for (int i = t; i < 2048; i += 256) {
    u64 k = 0;
    if (i < 1500) k = ((u64)fkey(perP[img * 1500 + i]) << 11) | (u64)(2047 - i);
    sb[i] = k;
  }
  if (t == 0) ncnt = 0;
  bitonic_desc<2048, 256>(sb, t);
  int localn = 0;
  for (int r = t; r < 300; r += 256) {
    u64 k = sb[r];
    int idx = 2047 - (int)(k & 0x7FF);
    float p = perP[img * 1500 + idx];
    bool valid = p > 0.f;
    float4 b = make_float4(0, 0, 0, 0);
    if (valid) b = *(const float4*)&perB[(size_t)(img * 1500 + idx) * 4];
    float* o = out + (size_t)img * 1500 + (size_t)r * 5;
    o[0] = b.x; o[1] = b.y; o[2] = b.z; o[3] = b.w;
    o[4] = valid ? p : 0.f;
    if (valid) localn++;
  }
  atomicAdd(&ncnt, localn);
  __syncthreads();
  if (t == 0) nout[img] = (float)ncnt;
}

// ---------------- launch ----------------
extern "C" void kernel_launch(void* const* d_in, const int* in_sizes, int n_in,
                              void* d_out, int out_size, void* d_ws, size_t ws_size,
                              hipStream_t stream) {
  const float* f0   = (const float*)d_in[0];
  const float* f1   = (const float*)d_in[1];
  const float* f2   = (const float*)d_in[2];
  const float* f3   = (const float*)d_in[3];
  const float* f4   = (const float*)d_in[4];
  const float* imsh = (const float*)d_in[5];
  const float* Wf   = (const float*)d_in[6];
  const float* bfv  = (const float*)d_in[7];
  const float* Wsc  = (const float*)d_in[8];
  const float* bsc  = (const float*)d_in[9];
  const float* Wdl  = (const float*)d_in[10];
  const float* bdl  = (const float*)d_in[11];

  const size_t rfF_fused = 17459200;   // 512 * 34100 (all levels coexist)
  const size_t rfF_seq   = 13107200;   // L0 only; L1-4 shifted down after proj(L0)
  const size_t tailF     = 204600 + 818400 + 10000 + 40000 + 3000 + 12000 + 884736;
  const bool fused = (ws_size >= (rfF_fused + tailF) * 4);
  const size_t rfF = fused ? rfF_fused : rfF_seq;

  float* ws     = (float*)d_ws;
  float* rfbuf  = ws;
  u64*  mask    = (u64*)d_ws;                // overlay: used only after proj done
  float* probs  = rfbuf + rfF;               // 204,600
  float* boxesb = probs + 204600;            // 818,400
  float* topP   = boxesb + 818400;           // 10,000
  float* topB   = topP + 10000;              // 40,000
  float* perP   = topB + 40000;              // 3,000
  float* perB   = perP + 3000;               // 12,000
  u32*  Wt32    = (u32*)(perB + 12000);      // 884,736 u32

  prep_weights<<<2304, 256, 0, stream>>>(Wf, (unsigned short*)Wt32);

  if (fused) {
    conv_mega<<<1092, 256, 0, stream>>>(f0, f1, f2, f3, f4, Wt32, bfv, rfbuf, 0, 0);
    proj_mega<<<268, 256, 0, stream>>>(rfbuf, Wsc, bsc, Wdl, bdl, imsh, probs, boxesb, 0, 0);
  } else {
    conv_mega<<<800, 256, 0, stream>>>(f0, f1, f2, f3, f4, Wt32, bfv, rfbuf, 0, 1);
    proj_mega<<<200, 256, 0, stream>>>(rfbuf, Wsc, bsc, Wdl, bdl, imsh, probs, boxesb, 0, 1);
    conv_mega<<<292, 256, 0, stream>>>(f0, f1, f2, f3, f4, Wt32, bfv, rfbuf, 800, 1);
    proj_mega<<<68, 256, 0, stream>>>(rfbuf, Wsc, bsc, Wdl, bdl, imsh, probs, boxesb, 200, 1);
  }
  topk_level<<<10, 1024, 0, stream>>>(probs, boxesb, topP, topB);
  {
    dim3 gm(63, 10);
    nms_mask<<<gm, 256, 0, stream>>>(topB, mask);
  }
  nms_scan<<<10, 256, 0, stream>>>(topP, topB, mask, perP, perB);
  final_topk<<<2, 256, 0, stream>>>(perP, perB, (float*)d_out, (float*)d_out + 3000);
}